// Round 1
// baseline (560.595 us; speedup 1.0000x reference)
//
#include <hip/hip_runtime.h>
#include <math.h>

// Problem constants (fixed-shape problem)
#define NN 131072   // nodes
#define G  256      // groups
#define E  384      // embed
#define H  6        // heads
#define DH 64       // head dim
#define OUTD 256    // output dim
#define MAXN 1024   // max segment length

#define CHK 32      // nodes per chunk (one wave per chunk)
#define SLOTS 32    // max chunks per group (ceil(MAXN/CHK))
#define PART_STRIDE 2316   // 6*384 acc + 6 m + 6 l

// Workspace layout (float indices)
#define WS_QK   0                       // 6*384 folded q@Wk
#define WS_C    2304                    // 6 folded q@bk
#define WS_OFF  2432                    // 256 int32 segment offsets
#define WS_QV   2944                    // 384 projected+scaled query
#define WS_WL   3328                    // 8192 int32 worklist (g<<5|s)
#define WS_M    11520                   // 1 int32 worklist count
#define WS_CS   11776                   // 256 int32 exclusive chunk-count scan
#define WS_PART 12288                   // 8192 slots x 2316 partials
#define WS_WVT  (WS_PART + G*SLOTS*PART_STRIDE)  // 384x384 Wv^T [e][i]
#define WS_WOT  (WS_WVT + E*E)          // 384x384 Wo^T [e][i]
#define WS_WPT  (WS_WOT + E*E)          // 384x256 Wp^T [e][o]

// ---------------------------------------------------------------------------
// K0a: block 0: offset scan + chunk-count scan + compacted worklist.
// blocks 1..96: qv rows.  qv = 0.125*(query@Wq.T + bq)
// ---------------------------------------------------------------------------
__global__ __launch_bounds__(256) void k0a_scan_qv(
    const int* __restrict__ sizes, const float* __restrict__ query,
    const float* __restrict__ Wq, const float* __restrict__ bq,
    float* __restrict__ wsf) {
  const int tid = threadIdx.x;
  if (blockIdx.x == 0) {
    __shared__ int s_scan[G];
    __shared__ int s_scan2[G];
    const int sz = sizes[tid];
    s_scan[tid] = sz;
    const int nch = (sz + CHK - 1) >> 5;           // 1..32
    s_scan2[tid] = nch;
    __syncthreads();
    for (int d = 1; d < G; d <<= 1) {
      int t = (tid >= d) ? s_scan[tid - d] : 0;
      int t2 = (tid >= d) ? s_scan2[tid - d] : 0;
      __syncthreads();
      s_scan[tid] += t;
      s_scan2[tid] += t2;
      __syncthreads();
    }
    ((int*)(wsf + WS_OFF))[tid] = s_scan[tid] - sz;    // exclusive node offset
    const int pos = s_scan2[tid] - nch;
    ((int*)(wsf + WS_CS))[tid] = pos;                  // exclusive chunk scan
    int* wl = (int*)(wsf + WS_WL);
    for (int s = 0; s < nch; s++) wl[pos + s] = (tid << 5) | s;
    if (tid == G - 1) ((int*)(wsf + WS_M))[0] = s_scan2[G - 1];
  } else {
    const int lane = tid & 63;
    const int i = (blockIdx.x - 1) * 4 + (tid >> 6);   // 0..383
    float a = 0.f;
#pragma unroll
    for (int j = 0; j < 6; j++)
      a += Wq[(size_t)i * E + j * 64 + lane] * query[j * 64 + lane];
#pragma unroll
    for (int mm = 1; mm < 64; mm <<= 1) a += __shfl_xor(a, mm, 64);
    if (lane == 0) wsf[WS_QV + i] = 0.125f * (a + bq[i]);
  }
}

// ---------------------------------------------------------------------------
// K0b: qk[h][e] = sum_d qv[h*64+d]*Wk[h*64+d][e].  36 blocks = (h, e-chunk64).
// ---------------------------------------------------------------------------
__global__ __launch_bounds__(256) void k0b_qk(
    const float* __restrict__ Wk, const float* __restrict__ bk,
    float* __restrict__ wsf) {
  __shared__ float qv_s[64];
  __shared__ float ps[256];
  const int h = blockIdx.x / 6, ec = blockIdx.x % 6;
  const int tid = threadIdx.x;
  if (tid < 64) qv_s[tid] = wsf[WS_QV + h * 64 + tid];
  __syncthreads();
  const int el = tid & 63, dq = tid >> 6;
  float a = 0.f;
#pragma unroll 4
  for (int d = dq * 16; d < dq * 16 + 16; d++)
    a += qv_s[d] * Wk[(size_t)(h * 64 + d) * E + ec * 64 + el];
  ps[tid] = a;
  __syncthreads();
  if (tid < 64)
    wsf[WS_QK + h * E + ec * 64 + tid] =
        ps[tid] + ps[64 + tid] + ps[128 + tid] + ps[192 + tid];
  if (ec == 0 && tid < 64) {                       // wave 0: c[h]
    float p = qv_s[tid] * bk[h * 64 + tid];
#pragma unroll
    for (int mm = 1; mm < 64; mm <<= 1) p += __shfl_xor(p, mm, 64);
    if (tid == 0) wsf[WS_C + h] = p;
  }
}

// ---------------------------------------------------------------------------
// K0t: transpose Wv, Wo (384x384) and Wp (256x384) into ws, 64x64 LDS tiles.
// ---------------------------------------------------------------------------
__global__ __launch_bounds__(256) void k0t_transpose(
    const float* __restrict__ Wv, const float* __restrict__ Wo,
    const float* __restrict__ Wp, float* __restrict__ wsf) {
  __shared__ float s[64][65];
  const int b = blockIdx.x;
  const float* src;
  float* dst;
  int R, tr, tc;
  if (b < 36)      { src = Wv; dst = wsf + WS_WVT; R = 384; tr = b / 6;        tc = b % 6; }
  else if (b < 72) { src = Wo; dst = wsf + WS_WOT; R = 384; tr = (b - 36) / 6; tc = (b - 36) % 6; }
  else             { src = Wp; dst = wsf + WS_WPT; R = 256; tr = (b - 72) / 6; tc = (b - 72) % 6; }
  const int r0 = tr * 64, c0 = tc * 64;
#pragma unroll
  for (int k = 0; k < 16; k++) {
    int idx = k * 256 + threadIdx.x;
    int r = idx >> 6, cc = idx & 63;
    s[r][cc] = src[(size_t)(r0 + r) * E + c0 + cc];
  }
  __syncthreads();
#pragma unroll
  for (int k = 0; k < 16; k++) {
    int idx = k * 256 + threadIdx.x;
    int cc = idx >> 6, r = idx & 63;
    dst[(size_t)(c0 + cc) * R + r0 + r] = s[r][cc];
  }
}

// ---------------------------------------------------------------------------
// K12 v6: ONE WAVE per 32-node chunk, single pass over x with in-register
// online softmax.  Previous version read x twice (scores, then pooling) and
// averaged 0.3 outstanding loads/wave at 1.85 TB/s (latency-bound).
// New design per lane (owns cols {k*64+lane}, k=0..5):
//   qk[6][6] fragment in VGPRs (loaded once; no LDS in the hot loop),
//   per node: 6 coalesced dword loads -> 36 score FMAs -> 6-head butterfly
//   reduce -> online-max rescale (wave-uniform, rare) -> 36 pooling FMAs on
//   the SAME registers.  x is fetched from HBM exactly once (halves traffic);
//   ping-pong prefetch keeps ~6 loads in flight per wave.
// Partial layout (2304 acc + 6 m + 6 l per slot) unchanged -> k3 untouched.
// ---------------------------------------------------------------------------
__global__ __launch_bounds__(256, 3) void k12_fused(
    const float* __restrict__ x, const int* __restrict__ sizes,
    float* __restrict__ wsf) {
  const int M = ((const int*)(wsf + WS_M))[0];
  const int lane = threadIdx.x & 63;
  const int it = blockIdx.x * 4 + (threadIdx.x >> 6);  // chunk per wave
  if (it >= M) return;
  const int item = ((const int*)(wsf + WS_WL))[it];
  const int g = item >> 5, s = item & 31;
  const int rem = sizes[g] - s * CHK;
  const int clen = rem < CHK ? rem : CHK;
  const int n0 = ((const int*)(wsf + WS_OFF))[g] + s * CHK;

  // per-lane qk fragment and bias: qk[h][k] pairs with col k*64+lane
  float qk[6][6], cb[6];
#pragma unroll
  for (int h = 0; h < 6; h++) {
#pragma unroll
    for (int k = 0; k < 6; k++) qk[h][k] = wsf[WS_QK + h * E + k * 64 + lane];
    cb[h] = wsf[WS_C + h];
  }

  float m[6], l[6], acc[6][6];
#pragma unroll
  for (int h = 0; h < 6; h++) {
    m[h] = -3.0e38f;
    l[h] = 0.f;
#pragma unroll
    for (int k = 0; k < 6; k++) acc[h][k] = 0.f;
  }

  const float* xp = x + (size_t)n0 * E + lane;

  float xA[6], xB[6];
  auto loadx = [&](float (&b)[6], int n) {
    const float* p = xp + n * E;
#pragma unroll
    for (int k = 0; k < 6; k++) b[k] = p[k * 64];    // 6 coalesced dwords
  };
  auto compute = [&](const float (&xv)[6]) {
    float sr[6];
#pragma unroll
    for (int h = 0; h < 6; h++) {                    // score partial, 6 chains
      float a = qk[h][0] * xv[0];
#pragma unroll
      for (int k = 1; k < 6; k++) a = fmaf(qk[h][k], xv[k], a);
#pragma unroll
      for (int mm = 1; mm < 64; mm <<= 1) a += __shfl_xor(a, mm, 64);
      sr[h] = a + cb[h];                             // uniform across lanes
    }
    bool upd = false;
#pragma unroll
    for (int h = 0; h < 6; h++) upd = upd || (sr[h] > m[h]);
    if (upd) {                                       // wave-uniform, rare
#pragma unroll
      for (int h = 0; h < 6; h++) {
        const float nm = fmaxf(m[h], sr[h]);
        const float f = __expf(m[h] - nm);
        m[h] = nm;
        l[h] *= f;
#pragma unroll
        for (int k = 0; k < 6; k++) acc[h][k] *= f;
      }
    }
#pragma unroll
    for (int h = 0; h < 6; h++) {
      const float p = __expf(sr[h] - m[h]);
      l[h] += p;
#pragma unroll
      for (int k = 0; k < 6; k++) acc[h][k] = fmaf(p, xv[k], acc[h][k]);
    }
  };

  // ping-pong software pipeline: next node's loads issue before this compute
  loadx(xA, 0);
  int n = 0;
  while (true) {
    if (n + 1 < clen) {
      loadx(xB, n + 1);
      compute(xA);
      if (n + 2 < clen) {
        loadx(xA, n + 2);
        compute(xB);
        n += 2;
      } else {
        compute(xB);
        break;
      }
    } else {
      compute(xA);
      break;
    }
  }

  float* pslot = wsf + WS_PART + (size_t)it * PART_STRIDE;
#pragma unroll
  for (int h = 0; h < 6; h++)
#pragma unroll
    for (int k = 0; k < 6; k++)
      pslot[h * E + k * 64 + lane] = acc[h][k];      // coalesced dword stores
  if (lane < 6) {
    float vm = m[0], vl = l[0];
#pragma unroll
    for (int h = 1; h < 6; h++) {
      vm = (lane == h) ? m[h] : vm;
      vl = (lane == h) ? l[h] : vl;
    }
    pslot[2304 + lane] = vm;
    pslot[2310 + lane] = vl;
  }
}

// ---------------------------------------------------------------------------
// K3: one block (768 thr) per group.  Flash-combine <=32 chunk partials
// (m/l staged to LDS in parallel) -> xb; then thread-per-output chain on
// transposed weights (coalesced, L2-resident), K-split, combine via LDS.
// Combine inner loop 4-way unrolled (4 independent loads in flight/thread).
// ---------------------------------------------------------------------------
__global__ __launch_bounds__(768) void k3_group(
    const float* __restrict__ wsf, const int* __restrict__ sizes,
    const float* __restrict__ bv, const float* __restrict__ bo,
    const float* __restrict__ bp, float* __restrict__ out) {
  __shared__ float xb[H * E];          // 9.2 KB
  __shared__ float pooled[E];
  __shared__ float om[E];
  __shared__ float ps[768];
  __shared__ float msh[SLOTS][H], lsh[SLOTS][H], wgt[SLOTS][H];
  __shared__ float linv[H];
  const int tid = threadIdx.x;
  const int g = blockIdx.x;
  const int nch = (sizes[g] + CHK - 1) >> 5;       // 1..32
  const int base_s = ((const int*)(wsf + WS_CS))[g];
  const float* pg = wsf + WS_PART + (size_t)base_s * PART_STRIDE;
  const float* wvt = wsf + WS_WVT;
  const float* wot = wsf + WS_WOT;
  const float* wpt = wsf + WS_WPT;

  if (tid < SLOTS * H) {
    const int s2 = tid / H, h2 = tid % H;
    if (s2 < nch) {
      msh[s2][h2] = pg[(size_t)s2 * PART_STRIDE + 2304 + h2];
      lsh[s2][h2] = pg[(size_t)s2 * PART_STRIDE + 2310 + h2];
    }
  }
  __syncthreads();
  if (tid < H) {
    float m = -3.0e38f;
    for (int s = 0; s < nch; s++) m = fmaxf(m, msh[s][tid]);
    float L = 0.f;
    for (int s = 0; s < nch; s++) {
      float wv_ = __expf(msh[s][tid] - m);
      wgt[s][tid] = wv_;
      L += lsh[s][tid] * wv_;
    }
    linv[tid] = 1.f / L;
  }
  __syncthreads();
  for (int idx = tid; idx < H * E; idx += 768) {
    const int h = idx / E;
    const float* pp = pg + idx;
    float a0 = 0.f, a1 = 0.f, a2 = 0.f, a3 = 0.f;
    int s2 = 0;
    for (; s2 + 3 < nch; s2 += 4) {
      a0 += pp[(size_t)(s2 + 0) * PART_STRIDE] * wgt[s2 + 0][h];
      a1 += pp[(size_t)(s2 + 1) * PART_STRIDE] * wgt[s2 + 1][h];
      a2 += pp[(size_t)(s2 + 2) * PART_STRIDE] * wgt[s2 + 2][h];
      a3 += pp[(size_t)(s2 + 3) * PART_STRIDE] * wgt[s2 + 3][h];
    }
    for (; s2 < nch; s2++) a0 += pp[(size_t)s2 * PART_STRIDE] * wgt[s2][h];
    xb[idx] = ((a0 + a1) + (a2 + a3)) * linv[h];
  }
  __syncthreads();

  {  // stage 1: pooled[i] = Wv[i,:]·xb[head(i),:] + bv
    const int i = tid % 384, ks = tid / 384;
    const float* xh = xb + (i >> 6) * E + ks * 192;
    const float* wp_ = wvt + (size_t)(ks * 192) * E + i;
    float a0 = 0.f, a1 = 0.f, a2 = 0.f, a3 = 0.f;
#pragma unroll 4
    for (int e = 0; e < 192; e += 4) {
      a0 += wp_[(size_t)(e + 0) * E] * xh[e + 0];
      a1 += wp_[(size_t)(e + 1) * E] * xh[e + 1];
      a2 += wp_[(size_t)(e + 2) * E] * xh[e + 2];
      a3 += wp_[(size_t)(e + 3) * E] * xh[e + 3];
    }
    ps[tid] = (a0 + a1) + (a2 + a3);
  }
  __syncthreads();
  if (tid < 384) pooled[tid] = ps[tid] + ps[384 + tid] + bv[tid];
  __syncthreads();

  {  // stage 2: om[i] = Wo[i,:]·pooled + bo
    const int i = tid % 384, ks = tid / 384;
    const float* xh = pooled + ks * 192;
    const float* wp_ = wot + (size_t)(ks * 192) * E + i;
    float a0 = 0.f, a1 = 0.f, a2 = 0.f, a3 = 0.f;
#pragma unroll 4
    for (int e = 0; e < 192; e += 4) {
      a0 += wp_[(size_t)(e + 0) * E] * xh[e + 0];
      a1 += wp_[(size_t)(e + 1) * E] * xh[e + 1];
      a2 += wp_[(size_t)(e + 2) * E] * xh[e + 2];
      a3 += wp_[(size_t)(e + 3) * E] * xh[e + 3];
    }
    ps[tid] = (a0 + a1) + (a2 + a3);
  }
  __syncthreads();
  if (tid < 384) om[tid] = ps[tid] + ps[384 + tid] + bo[tid];
  __syncthreads();

  {  // stage 3: out[o] = Wp[o,:]·om + bp   (3-way K-split of 384)
    const int o = tid % 256, ks = tid / 256;
    const float* xh = om + ks * 128;
    const float* wp_ = wpt + (size_t)(ks * 128) * OUTD + o;
    float a0 = 0.f, a1 = 0.f, a2 = 0.f, a3 = 0.f;
#pragma unroll 4
    for (int e = 0; e < 128; e += 4) {
      a0 += wp_[(size_t)(e + 0) * OUTD] * xh[e + 0];
      a1 += wp_[(size_t)(e + 1) * OUTD] * xh[e + 1];
      a2 += wp_[(size_t)(e + 2) * OUTD] * xh[e + 2];
      a3 += wp_[(size_t)(e + 3) * OUTD] * xh[e + 3];
    }
    ps[tid] = (a0 + a1) + (a2 + a3);
  }
  __syncthreads();
  if (tid < 256)
    out[(size_t)g * OUTD + tid] = ps[tid] + ps[256 + tid] + ps[512 + tid] + bp[tid];
}

// ---------------------------------------------------------------------------
extern "C" void kernel_launch(void* const* d_in, const int* in_sizes, int n_in,
                              void* d_out, int out_size, void* d_ws, size_t ws_size,
                              hipStream_t stream) {
  const float* x     = (const float*)d_in[0];
  const int*   sizes = (const int*)d_in[1];
  const float* query = (const float*)d_in[2];
  const float* Wq    = (const float*)d_in[3];
  const float* bq    = (const float*)d_in[4];
  const float* Wk    = (const float*)d_in[5];
  const float* bk    = (const float*)d_in[6];
  const float* Wv    = (const float*)d_in[7];
  const float* bv    = (const float*)d_in[8];
  const float* Wo    = (const float*)d_in[9];
  const float* bo    = (const float*)d_in[10];
  const float* Wp    = (const float*)d_in[11];
  const float* bp    = (const float*)d_in[12];
  float* wsf = (float*)d_ws;
  float* out = (float*)d_out;

  hipLaunchKernelGGL(k0a_scan_qv, dim3(97), dim3(256), 0, stream,
                     sizes, query, Wq, bq, wsf);
  hipLaunchKernelGGL(k0b_qk, dim3(36), dim3(256), 0, stream, Wk, bk, wsf);
  hipLaunchKernelGGL(k0t_transpose, dim3(96), dim3(256), 0, stream,
                     Wv, Wo, Wp, wsf);
  // 1088 blocks x 4 waves = 4352 chunk slots (M <= 4344 guaranteed:
  // sum(sizes)=131072 -> M <= 131072/32 + 256*(31/32) = 4344)
  hipLaunchKernelGGL(k12_fused, dim3(1088), dim3(256), 0, stream,
                     x, sizes, wsf);
  hipLaunchKernelGGL(k3_group, dim3(G), dim3(768), 0, stream,
                     wsf, sizes, bv, bo, bp, out);
}

// Round 2
// 351.426 us; speedup vs baseline: 1.5952x; 1.5952x over previous
//
#include <hip/hip_runtime.h>
#include <math.h>

// Problem constants (fixed-shape problem)
#define NN 131072   // nodes
#define G  256      // groups
#define E  384      // embed
#define H  6        // heads
#define DH 64       // head dim
#define OUTD 256    // output dim
#define MAXN 1024   // max segment length

#define CHK 32      // nodes per chunk (one wave per chunk)
#define SLOTS 32    // max chunks per group (ceil(MAXN/CHK))
#define PART_STRIDE 2316   // 6*384 acc + 6 m + 6 l

// Workspace layout (float indices)
#define WS_QK   0                       // 6*384 folded q@Wk
#define WS_C    2304                    // 6 folded q@bk (UNUSED by k12: softmax shift-invariant)
#define WS_OFF  2432                    // 256 int32 segment offsets
#define WS_QV   2944                    // 384 projected+scaled query
#define WS_WL   3328                    // 8192 int32 worklist (g<<5|s)
#define WS_M    11520                   // 1 int32 worklist count
#define WS_CS   11776                   // 256 int32 exclusive chunk-count scan
#define WS_PART 12288                   // 8192 slots x 2316 partials
#define WS_WVT  (WS_PART + G*SLOTS*PART_STRIDE)  // 384x384 Wv^T [e][i]
#define WS_WOT  (WS_WVT + E*E)          // 384x384 Wo^T [e][i]
#define WS_WPT  (WS_WOT + E*E)          // 384x256 Wp^T [e][o]

// ---------------------------------------------------------------------------
// K0a: block 0: offset scan + chunk-count scan + compacted worklist.
// blocks 1..96: qv rows.  qv = 0.125*(query@Wq.T + bq)
// ---------------------------------------------------------------------------
__global__ __launch_bounds__(256) void k0a_scan_qv(
    const int* __restrict__ sizes, const float* __restrict__ query,
    const float* __restrict__ Wq, const float* __restrict__ bq,
    float* __restrict__ wsf) {
  const int tid = threadIdx.x;
  if (blockIdx.x == 0) {
    __shared__ int s_scan[G];
    __shared__ int s_scan2[G];
    const int sz = sizes[tid];
    s_scan[tid] = sz;
    const int nch = (sz + CHK - 1) >> 5;           // 1..32
    s_scan2[tid] = nch;
    __syncthreads();
    for (int d = 1; d < G; d <<= 1) {
      int t = (tid >= d) ? s_scan[tid - d] : 0;
      int t2 = (tid >= d) ? s_scan2[tid - d] : 0;
      __syncthreads();
      s_scan[tid] += t;
      s_scan2[tid] += t2;
      __syncthreads();
    }
    ((int*)(wsf + WS_OFF))[tid] = s_scan[tid] - sz;    // exclusive node offset
    const int pos = s_scan2[tid] - nch;
    ((int*)(wsf + WS_CS))[tid] = pos;                  // exclusive chunk scan
    int* wl = (int*)(wsf + WS_WL);
    for (int s = 0; s < nch; s++) wl[pos + s] = (tid << 5) | s;
    if (tid == G - 1) ((int*)(wsf + WS_M))[0] = s_scan2[G - 1];
  } else {
    const int lane = tid & 63;
    const int i = (blockIdx.x - 1) * 4 + (tid >> 6);   // 0..383
    float a = 0.f;
#pragma unroll
    for (int j = 0; j < 6; j++)
      a += Wq[(size_t)i * E + j * 64 + lane] * query[j * 64 + lane];
#pragma unroll
    for (int mm = 1; mm < 64; mm <<= 1) a += __shfl_xor(a, mm, 64);
    if (lane == 0) wsf[WS_QV + i] = 0.125f * (a + bq[i]);
  }
}

// ---------------------------------------------------------------------------
// K0b: qk[h][e] = sum_d qv[h*64+d]*Wk[h*64+d][e].  36 blocks = (h, e-chunk64).
// ---------------------------------------------------------------------------
__global__ __launch_bounds__(256) void k0b_qk(
    const float* __restrict__ Wk, const float* __restrict__ bk,
    float* __restrict__ wsf) {
  __shared__ float qv_s[64];
  __shared__ float ps[256];
  const int h = blockIdx.x / 6, ec = blockIdx.x % 6;
  const int tid = threadIdx.x;
  if (tid < 64) qv_s[tid] = wsf[WS_QV + h * 64 + tid];
  __syncthreads();
  const int el = tid & 63, dq = tid >> 6;
  float a = 0.f;
#pragma unroll 4
  for (int d = dq * 16; d < dq * 16 + 16; d++)
    a += qv_s[d] * Wk[(size_t)(h * 64 + d) * E + ec * 64 + el];
  ps[tid] = a;
  __syncthreads();
  if (tid < 64)
    wsf[WS_QK + h * E + ec * 64 + tid] =
        ps[tid] + ps[64 + tid] + ps[128 + tid] + ps[192 + tid];
  if (ec == 0 && tid < 64) {                       // wave 0: c[h] (unused, kept)
    float p = qv_s[tid] * bk[h * 64 + tid];
#pragma unroll
    for (int mm = 1; mm < 64; mm <<= 1) p += __shfl_xor(p, mm, 64);
    if (tid == 0) wsf[WS_C + h] = p;
  }
}

// ---------------------------------------------------------------------------
// K0t: transpose Wv, Wo (384x384) and Wp (256x384) into ws, 64x64 LDS tiles.
// ---------------------------------------------------------------------------
__global__ __launch_bounds__(256) void k0t_transpose(
    const float* __restrict__ Wv, const float* __restrict__ Wo,
    const float* __restrict__ Wp, float* __restrict__ wsf) {
  __shared__ float s[64][65];
  const int b = blockIdx.x;
  const float* src;
  float* dst;
  int R, tr, tc;
  if (b < 36)      { src = Wv; dst = wsf + WS_WVT; R = 384; tr = b / 6;        tc = b % 6; }
  else if (b < 72) { src = Wo; dst = wsf + WS_WOT; R = 384; tr = (b - 36) / 6; tc = (b - 36) % 6; }
  else             { src = Wp; dst = wsf + WS_WPT; R = 256; tr = (b - 72) / 6; tc = (b - 72) % 6; }
  const int r0 = tr * 64, c0 = tc * 64;
#pragma unroll
  for (int k = 0; k < 16; k++) {
    int idx = k * 256 + threadIdx.x;
    int r = idx >> 6, cc = idx & 63;
    s[r][cc] = src[(size_t)(r0 + r) * E + c0 + cc];
  }
  __syncthreads();
#pragma unroll
  for (int k = 0; k < 16; k++) {
    int idx = k * 256 + threadIdx.x;
    int cc = idx >> 6, r = idx & 63;
    dst[(size_t)(c0 + cc) * R + r0 + r] = s[r][cc];
  }
}

// ---------------------------------------------------------------------------
// Wave-wide butterfly sum.  Steps xor1/2/4/8 via DPP (VALU pipe, exact lane
// permutations); xor16/32 via shuffle (LDS pipe).  Cuts per-reduce LDS-pipe
// ops from 6 to 2 vs a pure __shfl_xor chain.
// ---------------------------------------------------------------------------
template <int CTRL>
__device__ __forceinline__ float dpp_radd(float v) {
  int t = __builtin_amdgcn_update_dpp(0, __float_as_int(v), CTRL, 0xf, 0xf, true);
  return v + __int_as_float(t);
}
__device__ __forceinline__ float wave_sum64(float v) {
  v = dpp_radd<0xB1>(v);   // quad_perm [1,0,3,2]  : xor 1
  v = dpp_radd<0x4E>(v);   // quad_perm [2,3,0,1]  : xor 2
  v = dpp_radd<0x141>(v);  // row_half_mirror      : xor 4
  v = dpp_radd<0x140>(v);  // row_mirror           : xor 8
  v += __shfl_xor(v, 16, 64);
  v += __shfl_xor(v, 32, 64);
  return v;
}

// ---------------------------------------------------------------------------
// K12 v7: one wave per 32-node chunk, single pass, in-register online softmax.
// v6 post-mortem: VGPR_Count=84 < ~102 live floats -> accumulators spilled to
// scratch (80 MB excess WRITE_SIZE, 90% stall).  v7 is spill-proof:
//  - 1-wave blocks, __launch_bounds__(64,2) -> 256-VGPR cap
//  - no lambdas, plain loop, all array indices compile-time (full unroll)
//  - cb[] dropped (softmax shift-invariant: q@bk is a global per-head const,
//    cancels in-chunk and in k3's flash combine)
//  - DPP-based reduce (4 of 6 butterfly steps on VALU pipe)
//  - defer-max threshold 8 (T13): rescale branch almost never taken
//  - depth-2 rotating prefetch (x0/x1/x2): ~12 loads in flight per wave
// ---------------------------------------------------------------------------
__global__ __launch_bounds__(64, 2) void k12_fused(
    const float* __restrict__ x, const int* __restrict__ sizes,
    float* __restrict__ wsf) {
  const int M = ((const int*)(wsf + WS_M))[0];
  const int it = blockIdx.x;
  if (it >= M) return;
  const int lane = threadIdx.x;                    // 0..63
  const int item = ((const int*)(wsf + WS_WL))[it];
  const int g = item >> 5, s = item & 31;
  const int rem = sizes[g] - s * CHK;
  const int clen = rem < CHK ? rem : CHK;
  const int n0 = ((const int*)(wsf + WS_OFF))[g] + s * CHK;

  // per-lane qk fragment: qk[h][k] pairs with column k*64+lane
  float qk[6][6];
#pragma unroll
  for (int h = 0; h < 6; h++)
#pragma unroll
    for (int k = 0; k < 6; k++) qk[h][k] = wsf[WS_QK + h * E + k * 64 + lane];

  float m[6], l[6], acc[6][6];
#pragma unroll
  for (int h = 0; h < 6; h++) {
    m[h] = -3.0e38f;
    l[h] = 0.f;
#pragma unroll
    for (int k = 0; k < 6; k++) acc[h][k] = 0.f;
  }

  const float* xp = x + (size_t)n0 * E + lane;

  float x0[6], x1[6], x2[6];
#define LOADX(buf, idx)                                            \
  {                                                                \
    const float* p_ = xp + (size_t)(idx) * E;                      \
    _Pragma("unroll") for (int k_ = 0; k_ < 6; k_++)               \
        buf[k_] = p_[k_ * 64];                                     \
  }
  LOADX(x0, 0);
  {
    const int i1 = (1 < clen) ? 1 : (clen - 1);
    LOADX(x1, i1);
  }

  for (int n = 0; n < clen; n++) {
    {  // prefetch n+2 (clamped; duplicate loads hit L1/L2, never accumulated)
      const int i2 = (n + 2 < clen) ? (n + 2) : (clen - 1);
      LOADX(x2, i2);
    }
    // scores: 6 independent FMA chains, then wave-wide reduce
    float sr[6];
#pragma unroll
    for (int h = 0; h < 6; h++) {
      float a = qk[h][0] * x0[0];
#pragma unroll
      for (int k = 1; k < 6; k++) a = fmaf(qk[h][k], x0[k], a);
      sr[h] = a;
    }
#pragma unroll
    for (int h = 0; h < 6; h++) sr[h] = wave_sum64(sr[h]);
    // deferred-max online softmax (rescale only when max grows by > 8)
    bool upd = false;
#pragma unroll
    for (int h = 0; h < 6; h++) upd = upd || (sr[h] > m[h] + 8.0f);
    if (upd) {
#pragma unroll
      for (int h = 0; h < 6; h++) {
        const float nm = fmaxf(m[h], sr[h]);
        const float f = __expf(m[h] - nm);
        m[h] = nm;
        l[h] *= f;
#pragma unroll
        for (int k = 0; k < 6; k++) acc[h][k] *= f;
      }
    }
#pragma unroll
    for (int h = 0; h < 6; h++) {
      const float p = __expf(sr[h] - m[h]);
      l[h] += p;
#pragma unroll
      for (int k = 0; k < 6; k++) acc[h][k] = fmaf(p, x0[k], acc[h][k]);
    }
    // rotate prefetch buffers (compile-time indices only)
#pragma unroll
    for (int k = 0; k < 6; k++) {
      x0[k] = x1[k];
      x1[k] = x2[k];
    }
  }
#undef LOADX

  float* pslot = wsf + WS_PART + (size_t)it * PART_STRIDE;
#pragma unroll
  for (int h = 0; h < 6; h++)
#pragma unroll
    for (int k = 0; k < 6; k++)
      pslot[h * E + k * 64 + lane] = acc[h][k];      // coalesced dword stores
  if (lane < 6) {
    float vm = m[0], vl = l[0];
#pragma unroll
    for (int h = 1; h < 6; h++) {
      vm = (lane == h) ? m[h] : vm;
      vl = (lane == h) ? l[h] : vl;
    }
    pslot[2304 + lane] = vm;
    pslot[2310 + lane] = vl;
  }
}

// ---------------------------------------------------------------------------
// K3: one block (768 thr) per group.  Flash-combine <=32 chunk partials
// (m/l staged to LDS in parallel) -> xb; then thread-per-output chain on
// transposed weights (coalesced, L2-resident), K-split, combine via LDS.
// Combine inner loop 4-way unrolled (4 independent loads in flight/thread).
// ---------------------------------------------------------------------------
__global__ __launch_bounds__(768) void k3_group(
    const float* __restrict__ wsf, const int* __restrict__ sizes,
    const float* __restrict__ bv, const float* __restrict__ bo,
    const float* __restrict__ bp, float* __restrict__ out) {
  __shared__ float xb[H * E];          // 9.2 KB
  __shared__ float pooled[E];
  __shared__ float om[E];
  __shared__ float ps[768];
  __shared__ float msh[SLOTS][H], lsh[SLOTS][H], wgt[SLOTS][H];
  __shared__ float linv[H];
  const int tid = threadIdx.x;
  const int g = blockIdx.x;
  const int nch = (sizes[g] + CHK - 1) >> 5;       // 1..32
  const int base_s = ((const int*)(wsf + WS_CS))[g];
  const float* pg = wsf + WS_PART + (size_t)base_s * PART_STRIDE;
  const float* wvt = wsf + WS_WVT;
  const float* wot = wsf + WS_WOT;
  const float* wpt = wsf + WS_WPT;

  if (tid < SLOTS * H) {
    const int s2 = tid / H, h2 = tid % H;
    if (s2 < nch) {
      msh[s2][h2] = pg[(size_t)s2 * PART_STRIDE + 2304 + h2];
      lsh[s2][h2] = pg[(size_t)s2 * PART_STRIDE + 2310 + h2];
    }
  }
  __syncthreads();
  if (tid < H) {
    float m = -3.0e38f;
    for (int s = 0; s < nch; s++) m = fmaxf(m, msh[s][tid]);
    float L = 0.f;
    for (int s = 0; s < nch; s++) {
      float wv_ = __expf(msh[s][tid] - m);
      wgt[s][tid] = wv_;
      L += lsh[s][tid] * wv_;
    }
    linv[tid] = 1.f / L;
  }
  __syncthreads();
  for (int idx = tid; idx < H * E; idx += 768) {
    const int h = idx / E;
    const float* pp = pg + idx;
    float a0 = 0.f, a1 = 0.f, a2 = 0.f, a3 = 0.f;
    int s2 = 0;
    for (; s2 + 3 < nch; s2 += 4) {
      a0 += pp[(size_t)(s2 + 0) * PART_STRIDE] * wgt[s2 + 0][h];
      a1 += pp[(size_t)(s2 + 1) * PART_STRIDE] * wgt[s2 + 1][h];
      a2 += pp[(size_t)(s2 + 2) * PART_STRIDE] * wgt[s2 + 2][h];
      a3 += pp[(size_t)(s2 + 3) * PART_STRIDE] * wgt[s2 + 3][h];
    }
    for (; s2 < nch; s2++) a0 += pp[(size_t)s2 * PART_STRIDE] * wgt[s2][h];
    xb[idx] = ((a0 + a1) + (a2 + a3)) * linv[h];
  }
  __syncthreads();

  {  // stage 1: pooled[i] = Wv[i,:]·xb[head(i),:] + bv
    const int i = tid % 384, ks = tid / 384;
    const float* xh = xb + (i >> 6) * E + ks * 192;
    const float* wp_ = wvt + (size_t)(ks * 192) * E + i;
    float a0 = 0.f, a1 = 0.f, a2 = 0.f, a3 = 0.f;
#pragma unroll 4
    for (int e = 0; e < 192; e += 4) {
      a0 += wp_[(size_t)(e + 0) * E] * xh[e + 0];
      a1 += wp_[(size_t)(e + 1) * E] * xh[e + 1];
      a2 += wp_[(size_t)(e + 2) * E] * xh[e + 2];
      a3 += wp_[(size_t)(e + 3) * E] * xh[e + 3];
    }
    ps[tid] = (a0 + a1) + (a2 + a3);
  }
  __syncthreads();
  if (tid < 384) pooled[tid] = ps[tid] + ps[384 + tid] + bv[tid];
  __syncthreads();

  {  // stage 2: om[i] = Wo[i,:]·pooled + bo
    const int i = tid % 384, ks = tid / 384;
    const float* xh = pooled + ks * 192;
    const float* wp_ = wot + (size_t)(ks * 192) * E + i;
    float a0 = 0.f, a1 = 0.f, a2 = 0.f, a3 = 0.f;
#pragma unroll 4
    for (int e = 0; e < 192; e += 4) {
      a0 += wp_[(size_t)(e + 0) * E] * xh[e + 0];
      a1 += wp_[(size_t)(e + 1) * E] * xh[e + 1];
      a2 += wp_[(size_t)(e + 2) * E] * xh[e + 2];
      a3 += wp_[(size_t)(e + 3) * E] * xh[e + 3];
    }
    ps[tid] = (a0 + a1) + (a2 + a3);
  }
  __syncthreads();
  if (tid < 384) om[tid] = ps[tid] + ps[384 + tid] + bo[tid];
  __syncthreads();

  {  // stage 3: out[o] = Wp[o,:]·om + bp   (3-way K-split of 384)
    const int o = tid % 256, ks = tid / 256;
    const float* xh = om + ks * 128;
    const float* wp_ = wpt + (size_t)(ks * 128) * OUTD + o;
    float a0 = 0.f, a1 = 0.f, a2 = 0.f, a3 = 0.f;
#pragma unroll 4
    for (int e = 0; e < 128; e += 4) {
      a0 += wp_[(size_t)(e + 0) * OUTD] * xh[e + 0];
      a1 += wp_[(size_t)(e + 1) * OUTD] * xh[e + 1];
      a2 += wp_[(size_t)(e + 2) * OUTD] * xh[e + 2];
      a3 += wp_[(size_t)(e + 3) * OUTD] * xh[e + 3];
    }
    ps[tid] = (a0 + a1) + (a2 + a3);
  }
  __syncthreads();
  if (tid < 256)
    out[(size_t)g * OUTD + tid] = ps[tid] + ps[256 + tid] + ps[512 + tid] + bp[tid];
}

// ---------------------------------------------------------------------------
extern "C" void kernel_launch(void* const* d_in, const int* in_sizes, int n_in,
                              void* d_out, int out_size, void* d_ws, size_t ws_size,
                              hipStream_t stream) {
  const float* x     = (const float*)d_in[0];
  const int*   sizes = (const int*)d_in[1];
  const float* query = (const float*)d_in[2];
  const float* Wq    = (const float*)d_in[3];
  const float* bq    = (const float*)d_in[4];
  const float* Wk    = (const float*)d_in[5];
  const float* bk    = (const float*)d_in[6];
  const float* Wv    = (const float*)d_in[7];
  const float* bv    = (const float*)d_in[8];
  const float* Wo    = (const float*)d_in[9];
  const float* bo    = (const float*)d_in[10];
  const float* Wp    = (const float*)d_in[11];
  const float* bp    = (const float*)d_in[12];
  float* wsf = (float*)d_ws;
  float* out = (float*)d_out;

  hipLaunchKernelGGL(k0a_scan_qv, dim3(97), dim3(256), 0, stream,
                     sizes, query, Wq, bq, wsf);
  hipLaunchKernelGGL(k0b_qk, dim3(36), dim3(256), 0, stream, Wk, bk, wsf);
  hipLaunchKernelGGL(k0t_transpose, dim3(96), dim3(256), 0, stream,
                     Wv, Wo, Wp, wsf);
  // 4352 one-wave blocks >= max M (sum(sizes)=131072 -> M <= 4344)
  hipLaunchKernelGGL(k12_fused, dim3(4352), dim3(64), 0, stream,
                     x, sizes, wsf);
  hipLaunchKernelGGL(k3_group, dim3(G), dim3(768), 0, stream,
                     wsf, sizes, bv, bo, bp, out);
}

// Round 3
// 338.920 us; speedup vs baseline: 1.6541x; 1.0369x over previous
//
#include <hip/hip_runtime.h>
#include <math.h>

// Problem constants (fixed-shape problem)
#define NN 131072   // nodes
#define G  256      // groups
#define E  384      // embed
#define H  6        // heads
#define DH 64       // head dim
#define OUTD 256    // output dim
#define MAXN 1024   // max segment length

// Workspace layout (float indices) -- partials region retained in layout but
// no longer used (fully fused pipeline writes no intermediates to HBM).
#define WS_QK   0                       // 6*384 folded q@Wk
#define WS_C    2304                    // 6 folded q@bk (unused: softmax shift-invariant)
#define WS_OFF  2432                    // 256 int32 segment offsets
#define WS_QV   2944                    // 384 projected+scaled query
#define WS_WVT  12288                   // 384x384 Wv^T [e][i]
#define WS_WOT  (WS_WVT + E*E)          // 384x384 Wo^T [e][i]
#define WS_WPT  (WS_WOT + E*E)          // 384x256 Wp^T [e][o]

// ---------------------------------------------------------------------------
// K0a: block 0: segment-offset scan.  blocks 1..96: qv rows.
// qv = 0.125*(query@Wq.T + bq)
// ---------------------------------------------------------------------------
__global__ __launch_bounds__(256) void k0a_scan_qv(
    const int* __restrict__ sizes, const float* __restrict__ query,
    const float* __restrict__ Wq, const float* __restrict__ bq,
    float* __restrict__ wsf) {
  const int tid = threadIdx.x;
  if (blockIdx.x == 0) {
    __shared__ int s_scan[G];
    const int sz = sizes[tid];
    s_scan[tid] = sz;
    __syncthreads();
    for (int d = 1; d < G; d <<= 1) {
      int t = (tid >= d) ? s_scan[tid - d] : 0;
      __syncthreads();
      s_scan[tid] += t;
      __syncthreads();
    }
    ((int*)(wsf + WS_OFF))[tid] = s_scan[tid] - sz;    // exclusive node offset
  } else {
    const int lane = tid & 63;
    const int i = (blockIdx.x - 1) * 4 + (tid >> 6);   // 0..383
    float a = 0.f;
#pragma unroll
    for (int j = 0; j < 6; j++)
      a += Wq[(size_t)i * E + j * 64 + lane] * query[j * 64 + lane];
#pragma unroll
    for (int mm = 1; mm < 64; mm <<= 1) a += __shfl_xor(a, mm, 64);
    if (lane == 0) wsf[WS_QV + i] = 0.125f * (a + bq[i]);
  }
}

// ---------------------------------------------------------------------------
// K0b: qk[h][e] = sum_d qv[h*64+d]*Wk[h*64+d][e].  36 blocks = (h, e-chunk64).
// ---------------------------------------------------------------------------
__global__ __launch_bounds__(256) void k0b_qk(
    const float* __restrict__ Wk, const float* __restrict__ bk,
    float* __restrict__ wsf) {
  __shared__ float qv_s[64];
  __shared__ float ps[256];
  const int h = blockIdx.x / 6, ec = blockIdx.x % 6;
  const int tid = threadIdx.x;
  if (tid < 64) qv_s[tid] = wsf[WS_QV + h * 64 + tid];
  __syncthreads();
  const int el = tid & 63, dq = tid >> 6;
  float a = 0.f;
#pragma unroll 4
  for (int d = dq * 16; d < dq * 16 + 16; d++)
    a += qv_s[d] * Wk[(size_t)(h * 64 + d) * E + ec * 64 + el];
  ps[tid] = a;
  __syncthreads();
  if (tid < 64)
    wsf[WS_QK + h * E + ec * 64 + tid] =
        ps[tid] + ps[64 + tid] + ps[128 + tid] + ps[192 + tid];
}

// ---------------------------------------------------------------------------
// K0t: transpose Wv, Wo (384x384) and Wp (256x384) into ws, 64x64 LDS tiles.
// ---------------------------------------------------------------------------
__global__ __launch_bounds__(256) void k0t_transpose(
    const float* __restrict__ Wv, const float* __restrict__ Wo,
    const float* __restrict__ Wp, float* __restrict__ wsf) {
  __shared__ float s[64][65];
  const int b = blockIdx.x;
  const float* src;
  float* dst;
  int R, tr, tc;
  if (b < 36)      { src = Wv; dst = wsf + WS_WVT; R = 384; tr = b / 6;        tc = b % 6; }
  else if (b < 72) { src = Wo; dst = wsf + WS_WOT; R = 384; tr = (b - 36) / 6; tc = (b - 36) % 6; }
  else             { src = Wp; dst = wsf + WS_WPT; R = 256; tr = (b - 72) / 6; tc = (b - 72) % 6; }
  const int r0 = tr * 64, c0 = tc * 64;
#pragma unroll
  for (int k = 0; k < 16; k++) {
    int idx = k * 256 + threadIdx.x;
    int r = idx >> 6, cc = idx & 63;
    s[r][cc] = src[(size_t)(r0 + r) * E + c0 + cc];
  }
  __syncthreads();
#pragma unroll
  for (int k = 0; k < 16; k++) {
    int idx = k * 256 + threadIdx.x;
    int cc = idx >> 6, r = idx & 63;
    dst[(size_t)(c0 + cc) * R + r0 + r] = s[r][cc];
  }
}

// ---------------------------------------------------------------------------
// Wave-wide butterfly sum.  Steps xor1/2/4/8 via DPP (VALU pipe); xor16/32
// via shuffle (LDS pipe).
// ---------------------------------------------------------------------------
template <int CTRL>
__device__ __forceinline__ float dpp_radd(float v) {
  int t = __builtin_amdgcn_update_dpp(0, __float_as_int(v), CTRL, 0xf, 0xf, true);
  return v + __int_as_float(t);
}
__device__ __forceinline__ float wave_sum64(float v) {
  v = dpp_radd<0xB1>(v);   // quad_perm [1,0,3,2]  : xor 1
  v = dpp_radd<0x4E>(v);   // quad_perm [2,3,0,1]  : xor 2
  v = dpp_radd<0x141>(v);  // row_half_mirror      : xor 4
  v = dpp_radd<0x140>(v);  // row_mirror           : xor 8
  v += __shfl_xor(v, 16, 64);
  v += __shfl_xor(v, 32, 64);
  return v;
}

// ---------------------------------------------------------------------------
// K12G v8: FULLY FUSED per-group kernel.  One 768-thread (12-wave) block per
// group (grid = 256 = #CUs).  Eliminates the 40 MB partial write + 40 MB read
// and the separate k3 launch of the previous 2-level structure.
//  phase 1: each wave = v7 register scheme (qk[6][6] in VGPRs, in-register
//           online softmax w/ defer-max, DPP reduce, depth-1 ping-pong
//           prefetch), nodes w, w+12, w+24...  x read from HBM exactly once.
//  phase 2: flash-combine the 12 waves in LDS (per-wave m/l -> global M, L;
//           rescale acc in-register; accumulate into 4 LDS slices over 3
//           barrier rounds; tree-sum + 1/L).
//  phase 3: k3's 3-stage GEMM chain (transposed weights, L2-resident),
//           output written directly.
// LDS ~44 KB (1 block/CU by design).  Spill-proof structure: no lambdas,
// all array indices compile-time, state ~115 VGPR < 170 cap (768,3).
// ---------------------------------------------------------------------------
__global__ __launch_bounds__(768, 3) void k12g_fused(
    const float* __restrict__ x, const int* __restrict__ sizes,
    const float* __restrict__ bv, const float* __restrict__ bo,
    const float* __restrict__ bp, float* __restrict__ out,
    const float* __restrict__ wsf) {
  __shared__ float xsl[4][H * E];      // 36.9 KB accumulation slices
  __shared__ float ps[768];
  __shared__ float pooled[E];
  __shared__ float om[E];
  __shared__ float msh[12][H], lsh[12][H], wgts[12][H];
  __shared__ float linv[H];

  const int tid = threadIdx.x;
  const int lane = tid & 63;
  const int w = tid >> 6;              // wave 0..11
  const int g = blockIdx.x;
  const int sz = sizes[g];
  const int n0 = ((const int*)(wsf + WS_OFF))[g];

  // per-lane qk fragment: qk[h][k] pairs with column k*64+lane
  float qk[6][6];
#pragma unroll
  for (int h = 0; h < 6; h++)
#pragma unroll
    for (int k = 0; k < 6; k++) qk[h][k] = wsf[WS_QK + h * E + k * 64 + lane];

  float m[6], l[6], acc[6][6];
#pragma unroll
  for (int h = 0; h < 6; h++) {
    m[h] = -3.0e38f;
    l[h] = 0.f;
#pragma unroll
    for (int k = 0; k < 6; k++) acc[h][k] = 0.f;
  }

  // ---- phase 1: wave w handles nodes w, w+12, w+24, ... ----
  const float* xp = x + (size_t)(n0 + w) * E + lane;
  const int cnt = (sz > w) ? ((sz - w + 11) / 12) : 0;

  float x0[6], x1[6];
#define LOADX(buf, i)                                              \
  {                                                                \
    const float* p_ = xp + (size_t)(i) * (12 * E);                 \
    _Pragma("unroll") for (int k_ = 0; k_ < 6; k_++)               \
        buf[k_] = p_[k_ * 64];                                     \
  }
#define COMPUTE(xv)                                                          \
  {                                                                          \
    float sr[6];                                                             \
    _Pragma("unroll") for (int h_ = 0; h_ < 6; h_++) {                       \
      float a_ = qk[h_][0] * xv[0];                                          \
      _Pragma("unroll") for (int k_ = 1; k_ < 6; k_++)                       \
          a_ = fmaf(qk[h_][k_], xv[k_], a_);                                 \
      sr[h_] = a_;                                                           \
    }                                                                        \
    _Pragma("unroll") for (int h_ = 0; h_ < 6; h_++)                         \
        sr[h_] = wave_sum64(sr[h_]);                                         \
    bool upd_ = false;                                                       \
    _Pragma("unroll") for (int h_ = 0; h_ < 6; h_++)                         \
        upd_ = upd_ || (sr[h_] > m[h_] + 8.0f);                              \
    if (upd_) {                                                              \
      _Pragma("unroll") for (int h_ = 0; h_ < 6; h_++) {                     \
        const float nm_ = fmaxf(m[h_], sr[h_]);                              \
        const float f_ = __expf(m[h_] - nm_);                                \
        m[h_] = nm_;                                                         \
        l[h_] *= f_;                                                         \
        _Pragma("unroll") for (int k_ = 0; k_ < 6; k_++) acc[h_][k_] *= f_;  \
      }                                                                      \
    }                                                                        \
    _Pragma("unroll") for (int h_ = 0; h_ < 6; h_++) {                       \
      const float p_ = __expf(sr[h_] - m[h_]);                               \
      l[h_] += p_;                                                           \
      _Pragma("unroll") for (int k_ = 0; k_ < 6; k_++)                       \
          acc[h_][k_] = fmaf(p_, xv[k_], acc[h_][k_]);                       \
    }                                                                        \
  }

  if (cnt > 0) {
    LOADX(x0, 0);
    int i = 0;
    while (true) {
      int ip = (i + 1 < cnt) ? i + 1 : i;    // clamped prefetch (L1 dup ok)
      LOADX(x1, ip);
      COMPUTE(x0);
      if (++i >= cnt) break;
      ip = (i + 1 < cnt) ? i + 1 : i;
      LOADX(x0, ip);
      COMPUTE(x1);
      if (++i >= cnt) break;
    }
  }
#undef LOADX
#undef COMPUTE

  // ---- phase 2: cross-wave flash combine in LDS ----
  if (lane == 0) {
#pragma unroll
    for (int h = 0; h < 6; h++) {
      msh[w][h] = m[h];
      lsh[w][h] = l[h];
    }
  }
  __syncthreads();
  if (tid < 6) {
    const int h = tid;
    float M = -3.0e38f;
    for (int s = 0; s < 12; s++) M = fmaxf(M, msh[s][h]);
    float L = 0.f;
    for (int s = 0; s < 12; s++) {
      const float wv_ = __expf(msh[s][h] - M);
      wgts[s][h] = wv_;
      L += lsh[s][h] * wv_;
    }
    linv[h] = 1.0f / L;
  }
  __syncthreads();
  {
    float wg[6];
#pragma unroll
    for (int h = 0; h < 6; h++) wg[h] = wgts[w][h];
#pragma unroll
    for (int h = 0; h < 6; h++)
#pragma unroll
      for (int k = 0; k < 6; k++) acc[h][k] *= wg[h];
  }
  // accumulate into 4 slices: round 0 waves 0-3 store, rounds 1-2 add
  {
    float* xs = &xsl[w & 3][0];
    if (w < 4) {
#pragma unroll
      for (int h = 0; h < 6; h++)
#pragma unroll
        for (int k = 0; k < 6; k++) xs[h * E + k * 64 + lane] = acc[h][k];
    }
    __syncthreads();
    if (w >= 4 && w < 8) {
#pragma unroll
      for (int h = 0; h < 6; h++)
#pragma unroll
        for (int k = 0; k < 6; k++) xs[h * E + k * 64 + lane] += acc[h][k];
    }
    __syncthreads();
    if (w >= 8) {
#pragma unroll
      for (int h = 0; h < 6; h++)
#pragma unroll
        for (int k = 0; k < 6; k++) xs[h * E + k * 64 + lane] += acc[h][k];
    }
    __syncthreads();
  }
  // tree-sum 4 slices + 1/L scale -> xsl[0] (each thread owns its idx set)
  for (int idx = tid; idx < H * E; idx += 768) {
    const int h = idx / E;
    xsl[0][idx] = ((xsl[0][idx] + xsl[1][idx]) + (xsl[2][idx] + xsl[3][idx]))
                  * linv[h];
  }
  __syncthreads();

  // ---- phase 3: GEMM chain (k3's proven 768-thread stages) ----
  const float* xb = &xsl[0][0];
  const float* wvt = wsf + WS_WVT;
  const float* wot = wsf + WS_WOT;
  const float* wpt = wsf + WS_WPT;

  {  // stage 1: pooled[i] = Wv[i,:]·xb[head(i),:] + bv
    const int i = tid % 384, ks = tid / 384;
    const float* xh = xb + (i >> 6) * E + ks * 192;
    const float* wp_ = wvt + (size_t)(ks * 192) * E + i;
    float a0 = 0.f, a1 = 0.f, a2 = 0.f, a3 = 0.f;
#pragma unroll 4
    for (int e = 0; e < 192; e += 4) {
      a0 += wp_[(size_t)(e + 0) * E] * xh[e + 0];
      a1 += wp_[(size_t)(e + 1) * E] * xh[e + 1];
      a2 += wp_[(size_t)(e + 2) * E] * xh[e + 2];
      a3 += wp_[(size_t)(e + 3) * E] * xh[e + 3];
    }
    ps[tid] = (a0 + a1) + (a2 + a3);
  }
  __syncthreads();
  if (tid < 384) pooled[tid] = ps[tid] + ps[384 + tid] + bv[tid];
  __syncthreads();

  {  // stage 2: om[i] = Wo[i,:]·pooled + bo
    const int i = tid % 384, ks = tid / 384;
    const float* xh = pooled + ks * 192;
    const float* wp_ = wot + (size_t)(ks * 192) * E + i;
    float a0 = 0.f, a1 = 0.f, a2 = 0.f, a3 = 0.f;
#pragma unroll 4
    for (int e = 0; e < 192; e += 4) {
      a0 += wp_[(size_t)(e + 0) * E] * xh[e + 0];
      a1 += wp_[(size_t)(e + 1) * E] * xh[e + 1];
      a2 += wp_[(size_t)(e + 2) * E] * xh[e + 2];
      a3 += wp_[(size_t)(e + 3) * E] * xh[e + 3];
    }
    ps[tid] = (a0 + a1) + (a2 + a3);
  }
  __syncthreads();
  if (tid < 384) om[tid] = ps[tid] + ps[384 + tid] + bo[tid];
  __syncthreads();

  {  // stage 3: out[o] = Wp[o,:]·om + bp   (3-way K-split of 384)
    const int o = tid % 256, ks = tid / 256;
    const float* xh = om + ks * 128;
    const float* wp_ = wpt + (size_t)(ks * 128) * OUTD + o;
    float a0 = 0.f, a1 = 0.f, a2 = 0.f, a3 = 0.f;
#pragma unroll 4
    for (int e = 0; e < 128; e += 4) {
      a0 += wp_[(size_t)(e + 0) * OUTD] * xh[e + 0];
      a1 += wp_[(size_t)(e + 1) * OUTD] * xh[e + 1];
      a2 += wp_[(size_t)(e + 2) * OUTD] * xh[e + 2];
      a3 += wp_[(size_t)(e + 3) * OUTD] * xh[e + 3];
    }
    ps[tid] = (a0 + a1) + (a2 + a3);
  }
  __syncthreads();
  if (tid < 256)
    out[(size_t)g * OUTD + tid] = ps[tid] + ps[256 + tid] + ps[512 + tid] + bp[tid];
}

// ---------------------------------------------------------------------------
extern "C" void kernel_launch(void* const* d_in, const int* in_sizes, int n_in,
                              void* d_out, int out_size, void* d_ws, size_t ws_size,
                              hipStream_t stream) {
  const float* x     = (const float*)d_in[0];
  const int*   sizes = (const int*)d_in[1];
  const float* query = (const float*)d_in[2];
  const float* Wq    = (const float*)d_in[3];
  const float* bq    = (const float*)d_in[4];
  const float* Wk    = (const float*)d_in[5];
  const float* bk    = (const float*)d_in[6];
  const float* Wv    = (const float*)d_in[7];
  const float* bv    = (const float*)d_in[8];
  const float* Wo    = (const float*)d_in[9];
  const float* bo    = (const float*)d_in[10];
  const float* Wp    = (const float*)d_in[11];
  const float* bp    = (const float*)d_in[12];
  float* wsf = (float*)d_ws;
  float* out = (float*)d_out;

  hipLaunchKernelGGL(k0a_scan_qv, dim3(97), dim3(256), 0, stream,
                     sizes, query, Wq, bq, wsf);
  hipLaunchKernelGGL(k0b_qk, dim3(36), dim3(256), 0, stream, Wk, bk, wsf);
  hipLaunchKernelGGL(k0t_transpose, dim3(96), dim3(256), 0, stream,
                     Wv, Wo, Wp, wsf);
  hipLaunchKernelGGL(k12g_fused, dim3(G), dim3(768), 0, stream,
                     x, sizes, bv, bo, bp, out, wsf);
}